// Round 6
// baseline (583.002 us; speedup 1.0000x reference)
//
#include <hip/hip_runtime.h>

// Round 6: r5 minus the LDS bottleneck.
// 256 blocks x 512 threads, 8 rows/block, dup-M tile (each lane owns 2 real
// cells, no cross-lane ops). Changes vs r5:
//  - x NEVER touches LDS: each lane's A-frag for kt0,1 is 8 consecutive
//    floats of its own row -> global_load_dwordx4 x4 (L1-cached, dup lanes
//    hit same lines), prefetched 1 step ahead, cvt to bf16 in the shadow.
//  - dup-on-READ: h stored once (frag rows 0..7); reading lanes use l16&7
//    (2-way same-address broadcast = free). h-writes halve (2/lane).
//  - staggered gate chains: gates 0,1 MFMA'd first (x-frags, no LDS wait),
//    their sigmoids issue while gates 2,3 MFMAs run (trans overlaps matrix).
// Weights register-resident (96 VGPR), ONE barrier/step.

#define Bsz   2048
#define Tlen  256
#define Fdim  64
#define Hdim  128
#define ROWS  8
#define NTH   512
#define TILE_E 512             // elems per kt tile (64 lanes x 8)
#define HBUF_E (4 * TILE_E)    // 4 h-tiles (K 64..191) = 4 KB per buffer

using bf16x8 = __attribute__((ext_vector_type(8))) __bf16;
using f32x4  = __attribute__((ext_vector_type(4))) float;

__device__ __forceinline__ float fast_rcp(float x) {
#if __has_builtin(__builtin_amdgcn_rcpf)
    return __builtin_amdgcn_rcpf(x);
#else
    return 1.0f / x;
#endif
}
__device__ __forceinline__ float fast_exp2(float x) {
#if __has_builtin(__builtin_amdgcn_exp2f)
    return __builtin_amdgcn_exp2f(x);
#else
    return exp2f(x);
#endif
}
__device__ __forceinline__ float fsig(float x) {
    return fast_rcp(1.0f + fast_exp2(-1.4426950408889634f * x));
}
__device__ __forceinline__ float ftanh(float x) {
    float e = fast_exp2(-2.8853900817779268f * x);   // exp(-2x)
    return (1.0f - e) * fast_rcp(1.0f + e);
}

__device__ __forceinline__ bf16x8 cvt8(float4 a, float4 b) {
    bf16x8 r;
    r[0]=(__bf16)a.x; r[1]=(__bf16)a.y; r[2]=(__bf16)a.z; r[3]=(__bf16)a.w;
    r[4]=(__bf16)b.x; r[5]=(__bf16)b.y; r[6]=(__bf16)b.z; r[7]=(__bf16)b.w;
    return r;
}

// elem index inside an h buffer for (frag_row 0..7, h-col hk 0..127)
__device__ __forceinline__ int helem(int row, int hk) {
    return (hk >> 5) * TILE_E + ((((hk >> 3) & 3) * 16 + row) * 8) + (hk & 7);
}

__global__ __launch_bounds__(NTH, 2)
void lstm_fused(const float* __restrict__ x,
                const float* __restrict__ W_ih,
                const float* __restrict__ W_hh,
                const float* __restrict__ b_ih,
                const float* __restrict__ b_hh,
                const float* __restrict__ W1,
                const float* __restrict__ b1,
                const float* __restrict__ W2,
                const float* __restrict__ b2,
                float* __restrict__ out)
{
    __shared__ __bf16 Hbuf[2][HBUF_E];      // 8 KB, h in frag order (rows 0..7)
    __shared__ float  hlast[ROWS * Hdim];   // 4 KB fp32 h_T for head
    __shared__ float  zbuf[ROWS * 32];

    const int tid  = threadIdx.x;
    const int w    = tid >> 6;
    const int lane = tid & 63;
    const int quad = lane >> 4;
    const int l16  = lane & 15;
    const int b0   = blockIdx.x * ROWS;

    // ---- weights, register-resident: x-part (2 kt) + h-part (4 kt) ----
    // lane holds B[k = kt*32 + quad*8 + j][n = g*128 + w*16 + l16]
    bf16x8 bwx[2][4], bwh[4][4];
    #pragma unroll
    for (int kt = 0; kt < 6; ++kt) {
        const int k0 = kt * 32 + quad * 8;
        #pragma unroll
        for (int g = 0; g < 4; ++g) {
            const int n = g * Hdim + w * 16 + l16;
            const float* p = (kt < 2) ? (W_ih + (size_t)n * Fdim + k0)
                                      : (W_hh + (size_t)n * Hdim + (k0 - Fdim));
            float4 lo = *(const float4*)p;
            float4 hi = *(const float4*)(p + 4);
            bf16x8 r = cvt8(lo, hi);
            if (kt < 2) bwx[kt][g] = r; else bwh[kt - 2][g] = r;
        }
    }
    float biasv[4];
    #pragma unroll
    for (int g = 0; g < 4; ++g) {
        const int n = g * Hdim + w * 16 + l16;
        biasv[g] = b_ih[n] + b_hh[n];
    }

    // ---- per-lane x source: row = l16&7, feats quad*8.. (kt0) / +32 (kt1) ----
    const float* xlp = x + (size_t)(b0 + (l16 & 7)) * (Tlen * Fdim) + quad * 8;

    // ---- h-frag read offset (dup-on-read: row = l16&7) ----
    const int hread = (quad * 16 + (l16 & 7)) * 8;     // elems, +kt*TILE_E

    // ---- elementwise cells (same mapping as r5): 2 real cells/lane ----
    const int r0  = (quad >> 1) * 2;
    const int brb = (quad & 1) * 4 + r0;               // batch rows brb, brb+1
    const int hc  = 16 * w + l16;                      // H-col 0..127
    const int hw0 = helem(brb,     hc);
    const int hw1 = helem(brb + 1, hc);

    // ---- init: zero Hbuf[0] (h0 = 0), preload x_0 frags ----
    #pragma unroll
    for (int i = 0; i < (2 * HBUF_E) / NTH; ++i)
        ((__bf16*)Hbuf)[tid + i * NTH] = (__bf16)0.0f;
    bf16x8 xf0, xf1;
    {
        float4 a0 = *(const float4*)(xlp);
        float4 a1 = *(const float4*)(xlp + 4);
        float4 a2 = *(const float4*)(xlp + 32);
        float4 a3 = *(const float4*)(xlp + 36);
        xf0 = cvt8(a0, a1);
        xf1 = cvt8(a2, a3);
    }
    __syncthreads();

    float cc0 = 0.0f, cc1 = 0.0f;

    for (int t = 0; t < Tlen; ++t) {
        const int p = t & 1;
        const __bf16* rb = Hbuf[p];
        __bf16*      wb  = (__bf16*)Hbuf[1 - p];

        // h fragments (issue immediately; lgkm hidden by x-part MFMAs)
        bf16x8 hf[4];
        #pragma unroll
        for (int kt = 0; kt < 4; ++kt)
            hf[kt] = *(const bf16x8*)&rb[kt * TILE_E + hread];

        // prefetch x_{t+1} (fp32, cvt at end of step)
        float4 xn0, xn1, xn2, xn3;
        const bool ldx = (t + 1) < Tlen;
        if (ldx) {
            const float* xp = xlp + (size_t)(t + 1) * Fdim;
            xn0 = *(const float4*)(xp);
            xn1 = *(const float4*)(xp + 4);
            xn2 = *(const float4*)(xp + 32);
            xn3 = *(const float4*)(xp + 36);
        }

        // gates 0,1: x-part first (register frags, no wait), then h-part
        f32x4 acc[4];
        #pragma unroll
        for (int g = 0; g < 2; ++g) {
            acc[g] = (f32x4){biasv[g], biasv[g], biasv[g], biasv[g]};
            acc[g] = __builtin_amdgcn_mfma_f32_16x16x32_bf16(xf0, bwx[0][g], acc[g], 0, 0, 0);
            acc[g] = __builtin_amdgcn_mfma_f32_16x16x32_bf16(xf1, bwx[1][g], acc[g], 0, 0, 0);
            #pragma unroll
            for (int kt = 0; kt < 4; ++kt)
                acc[g] = __builtin_amdgcn_mfma_f32_16x16x32_bf16(hf[kt], bwh[kt][g], acc[g], 0, 0, 0);
        }
        // sigmoids of i,f overlap gates 2,3's MFMAs (different pipes)
        float iv0 = fsig(acc[0][r0]), iv1 = fsig(acc[0][r0 + 1]);
        float fv0 = fsig(acc[1][r0]), fv1 = fsig(acc[1][r0 + 1]);
        #pragma unroll
        for (int g = 2; g < 4; ++g) {
            acc[g] = (f32x4){biasv[g], biasv[g], biasv[g], biasv[g]};
            acc[g] = __builtin_amdgcn_mfma_f32_16x16x32_bf16(xf0, bwx[0][g], acc[g], 0, 0, 0);
            acc[g] = __builtin_amdgcn_mfma_f32_16x16x32_bf16(xf1, bwx[1][g], acc[g], 0, 0, 0);
            #pragma unroll
            for (int kt = 0; kt < 4; ++kt)
                acc[g] = __builtin_amdgcn_mfma_f32_16x16x32_bf16(hf[kt], bwh[kt][g], acc[g], 0, 0, 0);
        }
        float gv0 = ftanh(acc[2][r0]), gv1 = ftanh(acc[2][r0 + 1]);
        float ov0 = fsig(acc[3][r0]),  ov1 = fsig(acc[3][r0 + 1]);

        cc0 = fv0 * cc0 + iv0 * gv0;
        float h0 = ov0 * ftanh(cc0);
        cc1 = fv1 * cc1 + iv1 * gv1;
        float h1 = ov1 * ftanh(cc1);

        wb[hw0] = (__bf16)h0;           // stored ONCE (dup happens at read)
        wb[hw1] = (__bf16)h1;
        if (t == Tlen - 1) {
            hlast[brb * Hdim + hc]       = h0;
            hlast[(brb + 1) * Hdim + hc] = h1;
        }

        if (ldx) {
            xf0 = cvt8(xn0, xn1);
            xf1 = cvt8(xn2, xn3);
        }
        __syncthreads();   // the ONLY barrier per step
    }

    // ---- head: z = relu(h @ W1^T + b1); out = sigmoid(z @ W2^T + b2) ----
    if (tid < ROWS * 32) {
        const int b = tid >> 5, n = tid & 31;
        const float4* w4 = (const float4*)(W1 + n * Hdim);
        const float4* h4 = (const float4*)(hlast + b * Hdim);
        float s = b1[n];
        #pragma unroll
        for (int kk = 0; kk < Hdim / 4; ++kk) {
            float4 wv = w4[kk];
            float4 hv = h4[kk];
            s += wv.x * hv.x + wv.y * hv.y + wv.z * hv.z + wv.w * hv.w;
        }
        zbuf[b * 32 + n] = fmaxf(s, 0.0f);
    }
    __syncthreads();
    if (tid < ROWS) {
        float s = b2[0];
        #pragma unroll
        for (int n = 0; n < 32; ++n) s += zbuf[tid * 32 + n] * W2[n];
        out[b0 + tid] = fsig(s);
    }
}

extern "C" void kernel_launch(void* const* d_in, const int* in_sizes, int n_in,
                              void* d_out, int out_size, void* d_ws, size_t ws_size,
                              hipStream_t stream) {
    const float* x    = (const float*)d_in[0];
    const float* W_ih = (const float*)d_in[1];
    const float* W_hh = (const float*)d_in[2];
    const float* b_ih = (const float*)d_in[3];
    const float* b_hh = (const float*)d_in[4];
    const float* W1   = (const float*)d_in[5];
    const float* b1   = (const float*)d_in[6];
    const float* W2   = (const float*)d_in[7];
    const float* b2   = (const float*)d_in[8];
    float* out = (float*)d_out;

    dim3 grid(Bsz / ROWS), block(NTH);
    lstm_fused<<<grid, block, 0, stream>>>(x, W_ih, W_hh, b_ih, b_hh, W1, b1, W2, b2, out);
}

// Round 7
// 365.149 us; speedup vs baseline: 1.5966x; 1.5966x over previous
//
#include <hip/hip_runtime.h>

// Round 7: r5 (best, 260us) + x-part software pipelining.
// 256 blocks x 512 threads, 8 rows/block, dup-on-WRITE M=16 tile (r5's
// proven layout: 2 real cells/lane, no cross-lane ops, conflicts OK).
// New: xacc(t+1) = bias + x(t+1)W_ih^T is computed AFTER step t's
// elementwise (barrier-skew shadow), so the post-barrier critical chain is
// only: 4x ds_read_b128 -> 16 h-MFMAs -> elementwise -> h-write -> barrier.
// x is staged TWO steps ahead (buffer p's x-slots hold x(t+1) during step t).
// Weights register-resident (96 VGPR), ONE barrier/step.

#define Bsz   2048
#define Tlen  256
#define Fdim  64
#define Hdim  128
#define ROWS  8
#define NTH   512
#define TILE_E 512            // elems per kt tile (64 lanes x 8)
#define NKT   6               // kt 0,1 = x (K 0..63), kt 2..5 = h (K 64..191)
#define BUF_E (NKT * TILE_E)  // 3072 bf16 = 6 KB per buffer

using bf16x8 = __attribute__((ext_vector_type(8))) __bf16;
using f32x4  = __attribute__((ext_vector_type(4))) float;

__device__ __forceinline__ float fast_rcp(float x) {
#if __has_builtin(__builtin_amdgcn_rcpf)
    return __builtin_amdgcn_rcpf(x);
#else
    return 1.0f / x;
#endif
}
__device__ __forceinline__ float fast_exp2(float x) {
#if __has_builtin(__builtin_amdgcn_exp2f)
    return __builtin_amdgcn_exp2f(x);
#else
    return exp2f(x);
#endif
}
__device__ __forceinline__ float fsig(float x) {
    return fast_rcp(1.0f + fast_exp2(-1.4426950408889634f * x));
}
__device__ __forceinline__ float ftanh(float x) {
    float e = fast_exp2(-2.8853900817779268f * x);   // exp(-2x)
    return (1.0f - e) * fast_rcp(1.0f + e);
}

__device__ __forceinline__ bf16x8 cvt8(float4 a, float4 b) {
    bf16x8 r;
    r[0]=(__bf16)a.x; r[1]=(__bf16)a.y; r[2]=(__bf16)a.z; r[3]=(__bf16)a.w;
    r[4]=(__bf16)b.x; r[5]=(__bf16)b.y; r[6]=(__bf16)b.z; r[7]=(__bf16)b.w;
    return r;
}

// frag-order elem index for logical A[frag_row][k]
__device__ __forceinline__ int frag_elem(int row, int k) {
    return (k >> 5) * TILE_E + ((((k >> 3) & 3) * 16 + row) * 8) + (k & 7);
}

__global__ __launch_bounds__(NTH, 2)
void lstm_fused(const float* __restrict__ x,
                const float* __restrict__ W_ih,
                const float* __restrict__ W_hh,
                const float* __restrict__ b_ih,
                const float* __restrict__ b_hh,
                const float* __restrict__ W1,
                const float* __restrict__ b1,
                const float* __restrict__ W2,
                const float* __restrict__ b2,
                float* __restrict__ out)
{
    __shared__ __bf16 Abuf[2][BUF_E];       // 12 KB, fragment-order A operand
    __shared__ float  hlast[ROWS * Hdim];   // 4 KB fp32 h_T for head
    __shared__ float  zbuf[ROWS * 32];

    const int tid  = threadIdx.x;
    const int w    = tid >> 6;
    const int lane = tid & 63;
    const int quad = lane >> 4;
    const int l16  = lane & 15;
    const int b0   = blockIdx.x * ROWS;

    // ---- weights, register-resident: x-part (2 kt) + h-part (4 kt) ----
    // lane holds B[k = kt*32 + quad*8 + j][n = g*128 + w*16 + l16]
    bf16x8 bwx[2][4], bwh[4][4];
    #pragma unroll
    for (int kt = 0; kt < NKT; ++kt) {
        const int k0 = kt * 32 + quad * 8;
        #pragma unroll
        for (int g = 0; g < 4; ++g) {
            const int n = g * Hdim + w * 16 + l16;
            const float* p = (kt < 2) ? (W_ih + (size_t)n * Fdim + k0)
                                      : (W_hh + (size_t)n * Hdim + (k0 - Fdim));
            float4 lo = *(const float4*)p;
            float4 hi = *(const float4*)(p + 4);
            bf16x8 r = cvt8(lo, hi);
            if (kt < 2) bwx[kt][g] = r; else bwh[kt - 2][g] = r;
        }
    }
    float biasv[4];
    #pragma unroll
    for (int g = 0; g < 4; ++g) {
        const int n = g * Hdim + w * 16 + l16;
        biasv[g] = b_ih[n] + b_hh[n];
    }

    // ---- x staging: threads 0..255 -> (row = tid&7, feat pair fp) ----
    // value written to frag rows row AND row+8 (dup-on-write, r5-proven)
    const bool sx_on  = tid < 256;
    const int  sx_row = tid & 7;
    const int  sx_fp  = (tid >> 3) & 31;
    const int  f0     = 2 * sx_fp;
    const float* xrp  = x + (size_t)(b0 + sx_row) * (Tlen * Fdim) + f0;
    const int sx_e0 = frag_elem(sx_row,     f0);   // f0 even -> 4B aligned
    const int sx_e1 = frag_elem(sx_row + 8, f0);

    // ---- elementwise cells (r5 mapping): 2 real cells/lane ----
    const int r0  = (quad >> 1) * 2;
    const int brb = (quad & 1) * 4 + r0;     // batch rows brb, brb+1
    const int hc  = 16 * w + l16;            // H-col 0..127
    const int h_e0a = frag_elem(brb,         Fdim + hc);
    const int h_e0b = frag_elem(brb + 8,     Fdim + hc);
    const int h_e1a = frag_elem(brb + 1,     Fdim + hc);
    const int h_e1b = frag_elem(brb + 1 + 8, Fdim + hc);

    // ---- init: zero buf0 (h0 = 0), stage x(1)->buf0, xacc(0) from global ----
    #pragma unroll
    for (int i = 0; i < BUF_E / NTH; ++i)
        Abuf[0][tid + i * NTH] = (__bf16)0.0f;
    __syncthreads();
    float2 xpre = make_float2(0.f, 0.f);
    if (sx_on) {
        float2 v1 = *(const float2*)(xrp + Fdim);     // x(1) -> buf0 x-slots
        __bf16 a1[2] = {(__bf16)v1.x, (__bf16)v1.y};
        *(uint*)&Abuf[0][sx_e0] = *(uint*)a1;
        *(uint*)&Abuf[0][sx_e1] = *(uint*)a1;
        xpre = *(const float2*)(xrp + 2 * Fdim);      // x(2), staged in step 0
    }
    // xacc(0) = bias + x(0) W_ih^T, x(0) frags loaded directly from global:
    // A[row=l16][k=quad*8+j (kt0) / 32+quad*8+j (kt1)], row dup via l16&7
    f32x4 xacc[4];
    {
        const float* x0p = x + (size_t)(b0 + (l16 & 7)) * (Tlen * Fdim) + quad * 8;
        float4 a0 = *(const float4*)(x0p);
        float4 a1 = *(const float4*)(x0p + 4);
        float4 a2 = *(const float4*)(x0p + 32);
        float4 a3 = *(const float4*)(x0p + 36);
        bf16x8 xi0 = cvt8(a0, a1), xi1 = cvt8(a2, a3);
        #pragma unroll
        for (int g = 0; g < 4; ++g) {
            xacc[g] = (f32x4){biasv[g], biasv[g], biasv[g], biasv[g]};
            xacc[g] = __builtin_amdgcn_mfma_f32_16x16x32_bf16(xi0, bwx[0][g], xacc[g], 0, 0, 0);
            xacc[g] = __builtin_amdgcn_mfma_f32_16x16x32_bf16(xi1, bwx[1][g], xacc[g], 0, 0, 0);
        }
    }
    __syncthreads();

    float cc0 = 0.0f, cc1 = 0.0f;

    for (int t = 0; t < Tlen; ++t) {
        const int p = t & 1;
        const __bf16* rb = Abuf[p];
        __bf16*      wbf = (__bf16*)Abuf[1 - p];

        // h(t-1) fragments: 4x conflict-free ds_read_b128 at lane*16B
        bf16x8 hf[4];
        #pragma unroll
        for (int kt = 0; kt < 4; ++kt)
            hf[kt] = *(const bf16x8*)&rb[(2 + kt) * TILE_E + lane * 8];
        // x(t+1) fragments (staged 2 steps ahead; consumed AFTER elementwise)
        bf16x8 xf0 = *(const bf16x8*)&rb[lane * 8];
        bf16x8 xf1 = *(const bf16x8*)&rb[TILE_E + lane * 8];

        // prefetch x(t+3) from global (staged next iteration)
        float2 xnext = make_float2(0.f, 0.f);
        if (sx_on && (t + 3) < Tlen)
            xnext = *(const float2*)(xrp + (size_t)(t + 3) * Fdim);

        // gates(t) = xacc(t) + h-part: 16 MFMAs, 4 independent chains
        f32x4 acc[4];
        #pragma unroll
        for (int g = 0; g < 4; ++g) acc[g] = xacc[g];
        #pragma unroll
        for (int kt = 0; kt < 4; ++kt) {
            #pragma unroll
            for (int g = 0; g < 4; ++g)
                acc[g] = __builtin_amdgcn_mfma_f32_16x16x32_bf16(hf[kt], bwh[kt][g], acc[g], 0, 0, 0);
        }

        // elementwise: 2 cells/lane straight from acc (no cross-lane ops)
        {
            float iv = fsig(acc[0][r0]);
            float fv = fsig(acc[1][r0]);
            float gv = ftanh(acc[2][r0]);
            float ov = fsig(acc[3][r0]);
            cc0 = fv * cc0 + iv * gv;
            float h = ov * ftanh(cc0);
            __bf16 hb = (__bf16)h;
            wbf[h_e0a] = hb;
            wbf[h_e0b] = hb;
            if (t == Tlen - 1) hlast[brb * Hdim + hc] = h;
        }
        {
            float iv = fsig(acc[0][r0 + 1]);
            float fv = fsig(acc[1][r0 + 1]);
            float gv = ftanh(acc[2][r0 + 1]);
            float ov = fsig(acc[3][r0 + 1]);
            cc1 = fv * cc1 + iv * gv;
            float h = ov * ftanh(cc1);
            __bf16 hb = (__bf16)h;
            wbf[h_e1a] = hb;
            wbf[h_e1b] = hb;
            if (t == Tlen - 1) hlast[(brb + 1) * Hdim + hc] = h;
        }

        // xacc(t+1) = bias + x(t+1) W_ih^T  -- off the critical path,
        // issues in the barrier-skew shadow after this wave's elementwise
        if ((t + 1) < Tlen) {
            #pragma unroll
            for (int g = 0; g < 4; ++g) {
                xacc[g] = (f32x4){biasv[g], biasv[g], biasv[g], biasv[g]};
                xacc[g] = __builtin_amdgcn_mfma_f32_16x16x32_bf16(xf0, bwx[0][g], xacc[g], 0, 0, 0);
                xacc[g] = __builtin_amdgcn_mfma_f32_16x16x32_bf16(xf1, bwx[1][g], xacc[g], 0, 0, 0);
            }
        }

        // stage x(t+2) (held in xpre) into the write buffer, both copies
        if (sx_on && (t + 2) < Tlen) {
            __bf16 xa[2] = {(__bf16)xpre.x, (__bf16)xpre.y};
            *(uint*)&wbf[sx_e0] = *(uint*)xa;
            *(uint*)&wbf[sx_e1] = *(uint*)xa;
        }
        xpre = xnext;
        __syncthreads();   // the ONLY barrier per step
    }

    // ---- head: z = relu(h @ W1^T + b1); out = sigmoid(z @ W2^T + b2) ----
    if (tid < ROWS * 32) {
        const int b = tid >> 5, n = tid & 31;
        const float4* w4 = (const float4*)(W1 + n * Hdim);
        const float4* h4 = (const float4*)(hlast + b * Hdim);
        float s = b1[n];
        #pragma unroll
        for (int kk = 0; kk < Hdim / 4; ++kk) {
            float4 wv = w4[kk];
            float4 hv = h4[kk];
            s += wv.x * hv.x + wv.y * hv.y + wv.z * hv.z + wv.w * hv.w;
        }
        zbuf[b * 32 + n] = fmaxf(s, 0.0f);
    }
    __syncthreads();
    if (tid < ROWS) {
        float s = b2[0];
        #pragma unroll
        for (int n = 0; n < 32; ++n) s += zbuf[tid * 32 + n] * W2[n];
        out[b0 + tid] = fsig(s);
    }
}

extern "C" void kernel_launch(void* const* d_in, const int* in_sizes, int n_in,
                              void* d_out, int out_size, void* d_ws, size_t ws_size,
                              hipStream_t stream) {
    const float* x    = (const float*)d_in[0];
    const float* W_ih = (const float*)d_in[1];
    const float* W_hh = (const float*)d_in[2];
    const float* b_ih = (const float*)d_in[3];
    const float* b_hh = (const float*)d_in[4];
    const float* W1   = (const float*)d_in[5];
    const float* b1   = (const float*)d_in[6];
    const float* W2   = (const float*)d_in[7];
    const float* b2   = (const float*)d_in[8];
    float* out = (float*)d_out;

    dim3 grid(Bsz / ROWS), block(NTH);
    lstm_fused<<<grid, block, 0, stream>>>(x, W_ih, W_hh, b_ih, b_hh, W1, b1, W2, b2, out);
}